// Round 15
// baseline (104.293 us; speedup 1.0000x reference)
//
#include <hip/hip_runtime.h>
#include <hip/hip_bf16.h>

#define B_ 8
#define N_ 1024
#define FIN_ 256
#define H_ 8
#define F_ 64
#define HF_ 512
#define BN_ 8192
#define LOG2E 1.4426950408889634f

using bf16x8 = __attribute__((ext_vector_type(8))) short;
using f32x4  = __attribute__((ext_vector_type(4))) float;
using i32x4  = __attribute__((ext_vector_type(4))) int;

__device__ __forceinline__ short f2bf(float x) {
  __hip_bfloat16 b = __float2bfloat16(x);
  return *reinterpret_cast<short*>(&b);
}
__device__ __forceinline__ float bf2f(short s) {
  union { unsigned u; float f; } v;
  v.u = ((unsigned)(unsigned short)s) << 16;
  return v.f;
}
__device__ __forceinline__ bf16x8 cvtCE(f32x4 pa, f32x4 pb, i32x4 ma, i32x4 mb, float es) {
  bf16x8 o;
#pragma unroll
  for (int e = 0; e < 4; e++) {
    o[e]     = f2bf(ma[e] != 0 ? es * pa[e] : -1e30f);
    o[e + 4] = f2bf(mb[e] != 0 ? es * pb[e] : -1e30f);
  }
  return o;
}

// K_prep: (a) cmat build with LDS transpose -> coalesced fragment-order writes,
// (b) xb/Wt bf16 conversion. (unchanged)
__global__ __launch_bounds__(256) void k_prep(
    const float* __restrict__ x, const float* __restrict__ W,
    const float* __restrict__ prior, const int* __restrict__ mask,
    const float* __restrict__ esp,
    short* __restrict__ xb, short* __restrict__ Wt, short* __restrict__ cmat) {
  const int bid = blockIdx.x;
  const int t   = threadIdx.x;
  if (bid >= 256) {
    const int cid = bid - 256;
    if (cid < 1024) {
      const int idx = (cid * 256 + t) * 8;
      f32x4 a = *(const f32x4*)(x + idx);
      f32x4 b = *(const f32x4*)(x + idx + 4);
      bf16x8 o;
      o[0]=f2bf(a[0]); o[1]=f2bf(a[1]); o[2]=f2bf(a[2]); o[3]=f2bf(a[3]);
      o[4]=f2bf(b[0]); o[5]=f2bf(b[1]); o[6]=f2bf(b[2]); o[7]=f2bf(b[3]);
      *(bf16x8*)(xb + idx) = o;
    } else {
      const int idx = (cid - 1024) * 256 + t;
      const int f = idx >> 8, c = idx & 255;
      Wt[f * FIN_ + c] = f2bf(W[c * HF_ + f]);
    }
    return;
  }
  __shared__ short stile[32768];
  const int b  = bid & 7;
  const int it = bid >> 3;
  const float es = esp[0] * LOG2E;
  const int r  = t >> 3;
  const int jb = (t & 7) * 8;
  const int frag = r >> 4, rl = r & 15;
  const size_t rowbase = ((size_t)b * N_ + it * 32 + r) * (size_t)N_;
#pragma unroll
  for (int jt = 0; jt < 16; jt++) {
    const int j = jt * 64 + jb;
    f32x4 p0 = *(const f32x4*)(prior + rowbase + j);
    f32x4 p1 = *(const f32x4*)(prior + rowbase + j + 4);
    i32x4 m0 = *(const i32x4*)(mask + rowbase + j);
    i32x4 m1 = *(const i32x4*)(mask + rowbase + j + 4);
    const int s = j >> 5;
    const int l = ((j >> 3) & 3) * 16 + rl;
    const int lsw = l ^ (2 * (l >> 4)) ^ ((s & 1) << 3);
    *(bf16x8*)(&stile[s * 1024 + frag * 512 + lsw * 8]) = cvtCE(p0, p1, m0, m1, es);
  }
  __syncthreads();
  short* cmt = cmat + (size_t)(b * 32 + it) * 32768;
#pragma unroll
  for (int k = 0; k < 16; k++) {
    const int g   = k * 2048 + t * 8;
    const int s   = g >> 10;
    const int rem = g & 1023;
    const int fr  = rem >> 9;
    const int l   = (rem >> 3) & 63;
    const int lsw = l ^ (2 * (l >> 4)) ^ ((s & 1) << 3);
    bf16x8 v = *(const bf16x8*)(&stile[s * 1024 + fr * 512 + lsw * 8]);
    *(bf16x8*)(cmt + g) = v;
  }
}

// K1: h = x@W per-head, fused el/er epilogue, hA fragment-order (unchanged).
__global__ __launch_bounds__(256) void k_h(
    const short* __restrict__ Wt, const short* __restrict__ xb,
    const float* __restrict__ aL, const float* __restrict__ aR,
    short* __restrict__ hAg, float* __restrict__ el_t, float* __restrict__ er_t) {
  const int nt = blockIdx.x;
  const int h  = blockIdx.y;
  const int w  = threadIdx.x >> 6;
  const int l  = threadIdx.x & 63;
  const int lr = l & 15, lk = l >> 4;
  const int n0 = nt * 64;
  const int fbase = h * 64 + w * 16;

  f32x4 acc[4] = {};
  const short* arow = Wt + (fbase + lr) * FIN_ + lk * 8;

#pragma unroll
  for (int k0 = 0; k0 < FIN_; k0 += 32) {
    bf16x8 a = *(const bf16x8*)(arow + k0);
#pragma unroll
    for (int nf = 0; nf < 4; nf++) {
      bf16x8 bb = *(const bf16x8*)(xb + (size_t)(n0 + nf * 16 + lr) * FIN_ + k0 + lk * 8);
      acc[nf] = __builtin_amdgcn_mfma_f32_16x16x32_bf16(a, bb, acc[nf], 0, 0, 0);
    }
  }

  __shared__ short sT[64][72];
  __shared__ float sEl[4][64], sEr[4][64];
  float al[4], ar[4];
#pragma unroll
  for (int r = 0; r < 4; r++) {
    const int fl = w * 16 + lk * 4 + r;
    al[r] = aL[h * F_ + fl];
    ar[r] = aR[h * F_ + fl];
  }
#pragma unroll
  for (int nf = 0; nf < 4; nf++) {
    const int nl = nf * 16 + lr;
#pragma unroll
    for (int r = 0; r < 4; r++)
      sT[w * 16 + lk * 4 + r][nl] = f2bf(acc[nf][r]);
    float pl = acc[nf][0]*al[0] + acc[nf][1]*al[1] + acc[nf][2]*al[2] + acc[nf][3]*al[3];
    float pr = acc[nf][0]*ar[0] + acc[nf][1]*ar[1] + acc[nf][2]*ar[2] + acc[nf][3]*ar[3];
    pl += __shfl_xor(pl, 16); pl += __shfl_xor(pl, 32);
    pr += __shfl_xor(pr, 16); pr += __shfl_xor(pr, 32);
    if (lk == 0) { sEl[w][nl] = pl; sEr[w][nl] = pr; }
  }
  __syncthreads();
  if (threadIdx.x < 64) {
    const int n = threadIdx.x;
    el_t[h * BN_ + n0 + n] = (sEl[0][n] + sEl[1][n] + sEl[2][n] + sEl[3][n]) * LOG2E;
    er_t[h * BN_ + n0 + n] = (sEr[0][n] + sEr[1][n] + sEr[2][n] + sEr[3][n]) * LOG2E;
  }
  const int b8h = (nt >> 4) * 8 + h;
  const int jb  = (nt & 15) * 2;
#pragma unroll
  for (int gi = 0; gi < 2; gi++) {
    const int g   = threadIdx.x * 2 + gi;
    const int jsl = g >> 8, ff = (g >> 6) & 3, gl = g & 63;
    const int glr = gl & 15, glk = gl >> 4;
    bf16x8 v = *(const bf16x8*)(&sT[ff * 16 + glr][jsl * 32 + glk * 8]);
    *(bf16x8*)(hAg + (((size_t)b8h * 32 + jb + jsl) * 4 + ff) * 512 + gl * 8) = v;
  }
}

// K2 v15: R13's scalar math (known-good) + j-split ONLY.
// Block = (b, hp, it): 8 waves = 4 heads x 2 j-halves (16 steps each).
// Depth-2 register pipeline; partial acc/denom combined via LDS.
// VGPR target ~115 -> __launch_bounds__(512,4) = 4 waves/SIMD.
#define PREFX(sn, Hd, E0d, E1d, Cd)                                   \
  {                                                                   \
    const short* hs_ = hW + (size_t)(sn) * 2048;                      \
    Hd[0] = *(const bf16x8*)(hs_);                                    \
    Hd[1] = *(const bf16x8*)(hs_ + 512);                              \
    Hd[2] = *(const bf16x8*)(hs_ + 1024);                             \
    Hd[3] = *(const bf16x8*)(hs_ + 1536);                             \
    E0d   = *(const f32x4*)(erp + (sn) * 32);                         \
    E1d   = *(const f32x4*)(erp + (sn) * 32 + 4);                     \
    Cd[0] = *(const bf16x8*)(cmW + (size_t)(sn) * 1024);              \
    Cd[1] = *(const bf16x8*)(cmW + (size_t)(sn) * 1024 + 512);        \
  }

#define COMP2(Hu, Cu, E0u, E1u)                                                \
  {                                                                            \
    bf16x8 pfA, pfB;                                                           \
    _Pragma("unroll")                                                          \
    for (int q = 0; q < 4; q++) {                                              \
      const float e0 = E0u[q], e1 = E1u[q];                                    \
      float sA  = el0 + e0, sA2 = el0 + e1;                                    \
      float sB  = el1 + e0, sB2 = el1 + e1;                                    \
      float vA  = fmaf(0.6f, sA,  bf2f(Cu[0][q]));                             \
      vA  = fmaf(0.4f, fabsf(sA),  vA);                                        \
      float vA2 = fmaf(0.6f, sA2, bf2f(Cu[0][q + 4]));                         \
      vA2 = fmaf(0.4f, fabsf(sA2), vA2);                                       \
      float vB  = fmaf(0.6f, sB,  bf2f(Cu[1][q]));                             \
      vB  = fmaf(0.4f, fabsf(sB),  vB);                                        \
      float vB2 = fmaf(0.6f, sB2, bf2f(Cu[1][q + 4]));                         \
      vB2 = fmaf(0.4f, fabsf(sB2), vB2);                                       \
      pfA[q]     = f2bf(__builtin_amdgcn_exp2f(vA));                           \
      pfA[q + 4] = f2bf(__builtin_amdgcn_exp2f(vA2));                          \
      pfB[q]     = f2bf(__builtin_amdgcn_exp2f(vB));                           \
      pfB[q + 4] = f2bf(__builtin_amdgcn_exp2f(vB2));                          \
    }                                                                          \
    __builtin_amdgcn_s_setprio(1);                                             \
    accSA   = __builtin_amdgcn_mfma_f32_16x16x32_bf16(ones, pfA, accSA, 0,0,0);\
    accSB   = __builtin_amdgcn_mfma_f32_16x16x32_bf16(ones, pfB, accSB, 0,0,0);\
    accA[0] = __builtin_amdgcn_mfma_f32_16x16x32_bf16(Hu[0], pfA, accA[0],0,0,0);\
    accB[0] = __builtin_amdgcn_mfma_f32_16x16x32_bf16(Hu[0], pfB, accB[0],0,0,0);\
    accA[1] = __builtin_amdgcn_mfma_f32_16x16x32_bf16(Hu[1], pfA, accA[1],0,0,0);\
    accB[1] = __builtin_amdgcn_mfma_f32_16x16x32_bf16(Hu[1], pfB, accB[1],0,0,0);\
    accA[2] = __builtin_amdgcn_mfma_f32_16x16x32_bf16(Hu[2], pfA, accA[2],0,0,0);\
    accB[2] = __builtin_amdgcn_mfma_f32_16x16x32_bf16(Hu[2], pfB, accB[2],0,0,0);\
    accA[3] = __builtin_amdgcn_mfma_f32_16x16x32_bf16(Hu[3], pfA, accA[3],0,0,0);\
    accB[3] = __builtin_amdgcn_mfma_f32_16x16x32_bf16(Hu[3], pfB, accB[3],0,0,0);\
    __builtin_amdgcn_s_setprio(0);                                             \
  }

__global__ __launch_bounds__(512, 4) void k_attn(
    const short* __restrict__ hAg, const float* __restrict__ el_t,
    const float* __restrict__ er_t, const short* __restrict__ cmat,
    float* __restrict__ out) {
  const int bid = blockIdx.x;
  const int b  = bid & 7;           // XCD = bid % 8
  const int hp = (bid >> 3) & 1;    // head half
  const int it = bid >> 4;          // 0..31
  const int t  = threadIdx.x;       // 512 thr = 8 waves
  const int w  = t >> 6;
  const int h  = hp * 4 + (w & 3);  // 4 heads per block
  const int jh = w >> 2;            // j-half: this wave covers 16 of 32 steps
  const int l  = t & 63;
  const int lr = l & 15, lk = l >> 4;
  const int i0 = it * 32;
  const size_t bn = (size_t)b * N_;

  __shared__ float red[4][64][36];  // partial-acc exchange (36 KB)

  const float el0 = el_t[h * BN_ + bn + i0 + lr];
  const float el1 = el_t[h * BN_ + bn + i0 + 16 + lr];
  const float* erp = er_t + h * BN_ + bn + lk * 8;
  const short* hW  = hAg + (size_t)(b * 8 + h) * 65536 + l * 8;
  const short* cmW = cmat + (size_t)(b * 32 + it) * 32768 + l * 8;

  bf16x8 HA[4], HB[4];
  bf16x8 cA[2], cB[2];
  f32x4 eA0, eA1, eB0, eB1;
  f32x4 accA[4] = {}, accB[4] = {};
  f32x4 accSA = {}, accSB = {};
  bf16x8 ones;
#pragma unroll
  for (int e = 0; e < 8; e++) ones[e] = (short)0x3F80;

  const int s0 = jh * 16;
  PREFX(s0, HA, eA0, eA1, cA);
  PREFX(s0 + 1, HB, eB0, eB1, cB);

  for (int s = s0; s < s0 + 16; s += 2) {  // branchless tail: overrun reads pad
    COMP2(HA, cA, eA0, eA1);  PREFX(s + 2, HA, eA0, eA1, cA);
    COMP2(HB, cB, eB0, eB1);  PREFX(s + 3, HB, eB0, eB1, cB);
  }

  // ---- combine j-halves ----
  if (jh) {
    float* rb = &red[w & 3][l][0];
#pragma unroll
    for (int ff = 0; ff < 4; ff++)
#pragma unroll
      for (int e = 0; e < 4; e++) {
        rb[ff * 4 + e]      = accA[ff][e];
        rb[16 + ff * 4 + e] = accB[ff][e];
      }
    rb[32] = accSA[0];
    rb[33] = accSB[0];
  }
  __syncthreads();
  if (!jh) {
    const float* rb = &red[w & 3][l][0];
#pragma unroll
    for (int ff = 0; ff < 4; ff++)
#pragma unroll
      for (int e = 0; e < 4; e++) {
        accA[ff][e] += rb[ff * 4 + e];
        accB[ff][e] += rb[16 + ff * 4 + e];
      }
    const float invA = 1.0f / (accSA[0] + rb[32]);
    const float invB = 1.0f / (accSB[0] + rb[33]);
    const size_t rowA = bn + i0 + lr;
    const size_t rowB = rowA + 16;
#pragma unroll
    for (int ff = 0; ff < 4; ff++) {
      f32x4 va = accA[ff], vb = accB[ff];
      va[0]*=invA; va[1]*=invA; va[2]*=invA; va[3]*=invA;
      vb[0]*=invB; vb[1]*=invB; vb[2]*=invB; vb[3]*=invB;
      *(f32x4*)(out + rowA * HF_ + h * 64 + ff * 16 + lk * 4) = va;
      *(f32x4*)(out + rowB * HF_ + h * 64 + ff * 16 + lk * 4) = vb;
    }
  }
}

extern "C" void kernel_launch(void* const* d_in, const int* in_sizes, int n_in,
                              void* d_out, int out_size, void* d_ws, size_t ws_size,
                              hipStream_t stream) {
  const float* x     = (const float*)d_in[0];
  const int*   adj   = (const int*)  d_in[1];
  const float* prior = (const float*)d_in[2];
  const float* W     = (const float*)d_in[3];
  const float* aL    = (const float*)d_in[4];
  const float* aR    = (const float*)d_in[5];
  const float* es    = (const float*)d_in[6];
  float* out = (float*)d_out;

  char* ws = (char*)d_ws;
  short* hAg  = (short*)ws;                                 //  0 MB,  8 MB
  short* xb   = (short*)(ws + 8u  * 1024 * 1024);           //  8 MB,  4 MB
  short* Wt   = (short*)(ws + 12u * 1024 * 1024);           // 12 MB, 256 KB
  float* el_t = (float*)(ws + 12u * 1024 * 1024 + 262144);  // 256 KB
  float* er_t = (float*)(ws + 12u * 1024 * 1024 + 524288);  // 256 KB
  short* cmat = (short*)(ws + 13u * 1024 * 1024);           // 13 MB, 16 MB (+pad)

  hipLaunchKernelGGL(k_prep, dim3(1792), dim3(256), 0, stream,
                     x, W, prior, adj, es, xb, Wt, cmat);
  hipLaunchKernelGGL(k_h,   dim3(128, 8), dim3(256), 0, stream,
                     Wt, xb, aL, aR, hAg, el_t, er_t);
  hipLaunchKernelGGL(k_attn, dim3(512), dim3(512), 0, stream,
                     hAg, el_t, er_t, cmat, out);
}

// Round 16
// 64.949 us; speedup vs baseline: 1.6058x; 1.6058x over previous
//
#include <hip/hip_runtime.h>
#include <hip/hip_bf16.h>

#define B_ 8
#define N_ 1024
#define FIN_ 256
#define H_ 8
#define F_ 64
#define HF_ 512
#define BN_ 8192
#define LOG2E 1.4426950408889634f

using bf16x8 = __attribute__((ext_vector_type(8))) short;
using f32x4  = __attribute__((ext_vector_type(4))) float;
using i32x4  = __attribute__((ext_vector_type(4))) int;

__device__ __forceinline__ short f2bf(float x) {
  __hip_bfloat16 b = __float2bfloat16(x);
  return *reinterpret_cast<short*>(&b);
}
__device__ __forceinline__ float bf2f(short s) {
  union { unsigned u; float f; } v;
  v.u = ((unsigned)(unsigned short)s) << 16;
  return v.f;
}
__device__ __forceinline__ bf16x8 cvtCE(f32x4 pa, f32x4 pb, i32x4 ma, i32x4 mb, float es) {
  bf16x8 o;
#pragma unroll
  for (int e = 0; e < 4; e++) {
    o[e]     = f2bf(ma[e] != 0 ? es * pa[e] : -1e30f);
    o[e + 4] = f2bf(mb[e] != 0 ? es * pb[e] : -1e30f);
  }
  return o;
}

// K_prep: (a) cmat build with LDS transpose -> coalesced fragment-order writes,
// (b) xb/Wt bf16 conversion. (unchanged)
__global__ __launch_bounds__(256) void k_prep(
    const float* __restrict__ x, const float* __restrict__ W,
    const float* __restrict__ prior, const int* __restrict__ mask,
    const float* __restrict__ esp,
    short* __restrict__ xb, short* __restrict__ Wt, short* __restrict__ cmat) {
  const int bid = blockIdx.x;
  const int t   = threadIdx.x;
  if (bid >= 256) {
    const int cid = bid - 256;
    if (cid < 1024) {
      const int idx = (cid * 256 + t) * 8;
      f32x4 a = *(const f32x4*)(x + idx);
      f32x4 b = *(const f32x4*)(x + idx + 4);
      bf16x8 o;
      o[0]=f2bf(a[0]); o[1]=f2bf(a[1]); o[2]=f2bf(a[2]); o[3]=f2bf(a[3]);
      o[4]=f2bf(b[0]); o[5]=f2bf(b[1]); o[6]=f2bf(b[2]); o[7]=f2bf(b[3]);
      *(bf16x8*)(xb + idx) = o;
    } else {
      const int idx = (cid - 1024) * 256 + t;
      const int f = idx >> 8, c = idx & 255;
      Wt[f * FIN_ + c] = f2bf(W[c * HF_ + f]);
    }
    return;
  }
  __shared__ short stile[32768];
  const int b  = bid & 7;
  const int it = bid >> 3;
  const float es = esp[0] * LOG2E;
  const int r  = t >> 3;
  const int jb = (t & 7) * 8;
  const int frag = r >> 4, rl = r & 15;
  const size_t rowbase = ((size_t)b * N_ + it * 32 + r) * (size_t)N_;
#pragma unroll
  for (int jt = 0; jt < 16; jt++) {
    const int j = jt * 64 + jb;
    f32x4 p0 = *(const f32x4*)(prior + rowbase + j);
    f32x4 p1 = *(const f32x4*)(prior + rowbase + j + 4);
    i32x4 m0 = *(const i32x4*)(mask + rowbase + j);
    i32x4 m1 = *(const i32x4*)(mask + rowbase + j + 4);
    const int s = j >> 5;
    const int l = ((j >> 3) & 3) * 16 + rl;
    const int lsw = l ^ (2 * (l >> 4)) ^ ((s & 1) << 3);
    *(bf16x8*)(&stile[s * 1024 + frag * 512 + lsw * 8]) = cvtCE(p0, p1, m0, m1, es);
  }
  __syncthreads();
  short* cmt = cmat + (size_t)(b * 32 + it) * 32768;
#pragma unroll
  for (int k = 0; k < 16; k++) {
    const int g   = k * 2048 + t * 8;
    const int s   = g >> 10;
    const int rem = g & 1023;
    const int fr  = rem >> 9;
    const int l   = (rem >> 3) & 63;
    const int lsw = l ^ (2 * (l >> 4)) ^ ((s & 1) << 3);
    bf16x8 v = *(const bf16x8*)(&stile[s * 1024 + fr * 512 + lsw * 8]);
    *(bf16x8*)(cmt + g) = v;
  }
}

// K1: h = x@W per-head, fused el/er epilogue, hA fragment-order (unchanged).
__global__ __launch_bounds__(256) void k_h(
    const short* __restrict__ Wt, const short* __restrict__ xb,
    const float* __restrict__ aL, const float* __restrict__ aR,
    short* __restrict__ hAg, float* __restrict__ el_t, float* __restrict__ er_t) {
  const int nt = blockIdx.x;
  const int h  = blockIdx.y;
  const int w  = threadIdx.x >> 6;
  const int l  = threadIdx.x & 63;
  const int lr = l & 15, lk = l >> 4;
  const int n0 = nt * 64;
  const int fbase = h * 64 + w * 16;

  f32x4 acc[4] = {};
  const short* arow = Wt + (fbase + lr) * FIN_ + lk * 8;

#pragma unroll
  for (int k0 = 0; k0 < FIN_; k0 += 32) {
    bf16x8 a = *(const bf16x8*)(arow + k0);
#pragma unroll
    for (int nf = 0; nf < 4; nf++) {
      bf16x8 bb = *(const bf16x8*)(xb + (size_t)(n0 + nf * 16 + lr) * FIN_ + k0 + lk * 8);
      acc[nf] = __builtin_amdgcn_mfma_f32_16x16x32_bf16(a, bb, acc[nf], 0, 0, 0);
    }
  }

  __shared__ short sT[64][72];
  __shared__ float sEl[4][64], sEr[4][64];
  float al[4], ar[4];
#pragma unroll
  for (int r = 0; r < 4; r++) {
    const int fl = w * 16 + lk * 4 + r;
    al[r] = aL[h * F_ + fl];
    ar[r] = aR[h * F_ + fl];
  }
#pragma unroll
  for (int nf = 0; nf < 4; nf++) {
    const int nl = nf * 16 + lr;
#pragma unroll
    for (int r = 0; r < 4; r++)
      sT[w * 16 + lk * 4 + r][nl] = f2bf(acc[nf][r]);
    float pl = acc[nf][0]*al[0] + acc[nf][1]*al[1] + acc[nf][2]*al[2] + acc[nf][3]*al[3];
    float pr = acc[nf][0]*ar[0] + acc[nf][1]*ar[1] + acc[nf][2]*ar[2] + acc[nf][3]*ar[3];
    pl += __shfl_xor(pl, 16); pl += __shfl_xor(pl, 32);
    pr += __shfl_xor(pr, 16); pr += __shfl_xor(pr, 32);
    if (lk == 0) { sEl[w][nl] = pl; sEr[w][nl] = pr; }
  }
  __syncthreads();
  if (threadIdx.x < 64) {
    const int n = threadIdx.x;
    el_t[h * BN_ + n0 + n] = (sEl[0][n] + sEl[1][n] + sEl[2][n] + sEl[3][n]) * LOG2E;
    er_t[h * BN_ + n0 + n] = (sEr[0][n] + sEr[1][n] + sEr[2][n] + sEr[3][n]) * LOG2E;
  }
  const int b8h = (nt >> 4) * 8 + h;
  const int jb  = (nt & 15) * 2;
#pragma unroll
  for (int gi = 0; gi < 2; gi++) {
    const int g   = threadIdx.x * 2 + gi;
    const int jsl = g >> 8, ff = (g >> 6) & 3, gl = g & 63;
    const int glr = gl & 15, glk = gl >> 4;
    bf16x8 v = *(const bf16x8*)(&sT[ff * 16 + glr][jsl * 32 + glk * 8]);
    *(bf16x8*)(hAg + (((size_t)b8h * 32 + jb + jsl) * 4 + ff) * 512 + gl * 8) = v;
  }
}

// K2 v16: GEMM-style i-blocking. Block = (b, h, it∈0..3) = 256 i-rows, 8 waves
// x 32 rows. h-chunk (8 steps, 32KB) staged in LDS double-buffer, shared by all
// 8 waves -> hA global traffic 256MB -> 32MB. One barrier per chunk (3 total).
// c/er direct global (read-once, L2/L3). COMP2 math verbatim R13.
#define PREF_CE(sn, E0d, E1d, Cd)                                     \
  {                                                                   \
    E0d   = *(const f32x4*)(erp + (sn) * 32);                         \
    E1d   = *(const f32x4*)(erp + (sn) * 32 + 4);                     \
    Cd[0] = *(const bf16x8*)(cmW + (size_t)(sn) * 1024);              \
    Cd[1] = *(const bf16x8*)(cmW + (size_t)(sn) * 1024 + 512);        \
  }

#define PREF_HD(hb, sl, Hd)                                           \
  {                                                                   \
    const short* p_ = (hb) + (sl) * 2048 + l * 8;                     \
    Hd[0] = *(const bf16x8*)(p_);                                     \
    Hd[1] = *(const bf16x8*)(p_ + 512);                               \
    Hd[2] = *(const bf16x8*)(p_ + 1024);                              \
    Hd[3] = *(const bf16x8*)(p_ + 1536);                              \
  }

#define COMP2(Hu, Cu, E0u, E1u)                                                \
  {                                                                            \
    bf16x8 pfA, pfB;                                                           \
    _Pragma("unroll")                                                          \
    for (int q = 0; q < 4; q++) {                                              \
      const float e0 = E0u[q], e1 = E1u[q];                                    \
      float sA  = el0 + e0, sA2 = el0 + e1;                                    \
      float sB  = el1 + e0, sB2 = el1 + e1;                                    \
      float vA  = fmaf(0.6f, sA,  bf2f(Cu[0][q]));                             \
      vA  = fmaf(0.4f, fabsf(sA),  vA);                                        \
      float vA2 = fmaf(0.6f, sA2, bf2f(Cu[0][q + 4]));                         \
      vA2 = fmaf(0.4f, fabsf(sA2), vA2);                                       \
      float vB  = fmaf(0.6f, sB,  bf2f(Cu[1][q]));                             \
      vB  = fmaf(0.4f, fabsf(sB),  vB);                                        \
      float vB2 = fmaf(0.6f, sB2, bf2f(Cu[1][q + 4]));                         \
      vB2 = fmaf(0.4f, fabsf(sB2), vB2);                                       \
      pfA[q]     = f2bf(__builtin_amdgcn_exp2f(vA));                           \
      pfA[q + 4] = f2bf(__builtin_amdgcn_exp2f(vA2));                          \
      pfB[q]     = f2bf(__builtin_amdgcn_exp2f(vB));                           \
      pfB[q + 4] = f2bf(__builtin_amdgcn_exp2f(vB2));                          \
    }                                                                          \
    __builtin_amdgcn_s_setprio(1);                                             \
    accSA   = __builtin_amdgcn_mfma_f32_16x16x32_bf16(ones, pfA, accSA, 0,0,0);\
    accSB   = __builtin_amdgcn_mfma_f32_16x16x32_bf16(ones, pfB, accSB, 0,0,0);\
    accA[0] = __builtin_amdgcn_mfma_f32_16x16x32_bf16(Hu[0], pfA, accA[0],0,0,0);\
    accB[0] = __builtin_amdgcn_mfma_f32_16x16x32_bf16(Hu[0], pfB, accB[0],0,0,0);\
    accA[1] = __builtin_amdgcn_mfma_f32_16x16x32_bf16(Hu[1], pfA, accA[1],0,0,0);\
    accB[1] = __builtin_amdgcn_mfma_f32_16x16x32_bf16(Hu[1], pfB, accB[1],0,0,0);\
    accA[2] = __builtin_amdgcn_mfma_f32_16x16x32_bf16(Hu[2], pfA, accA[2],0,0,0);\
    accB[2] = __builtin_amdgcn_mfma_f32_16x16x32_bf16(Hu[2], pfB, accB[2],0,0,0);\
    accA[3] = __builtin_amdgcn_mfma_f32_16x16x32_bf16(Hu[3], pfA, accA[3],0,0,0);\
    accB[3] = __builtin_amdgcn_mfma_f32_16x16x32_bf16(Hu[3], pfB, accB[3],0,0,0);\
    __builtin_amdgcn_s_setprio(0);                                             \
  }

__global__ __launch_bounds__(512, 2) void k_attn(
    const short* __restrict__ hAg, const float* __restrict__ el_t,
    const float* __restrict__ er_t, const short* __restrict__ cmat,
    float* __restrict__ out) {
  const int bid = blockIdx.x;
  const int b  = bid & 7;            // XCD = bid % 8
  const int h  = (bid >> 3) & 7;
  const int it = bid >> 6;           // 0..3 (256-row i-tiles)
  const int t  = threadIdx.x;        // 512 thr = 8 waves
  const int w  = t >> 6;
  const int l  = t & 63;
  const int lr = l & 15, lk = l >> 4;
  const int i0 = it * 256 + w * 32;  // wave's 32 rows
  const int tw = it * 8 + w;         // 32-row tile index 0..31 (cmat tiling)
  const size_t bn = (size_t)b * N_;

  __shared__ short hbuf[2][16384];   // 2 x 32KB h-chunk (8 steps x 4 frags)

  const float el0 = el_t[h * BN_ + bn + i0 + lr];
  const float el1 = el_t[h * BN_ + bn + i0 + 16 + lr];
  const float* erp = er_t + h * BN_ + bn + lk * 8;
  const short* cmW = cmat + (size_t)(b * 32 + tw) * 32768 + l * 8;
  const short* hG  = hAg + (size_t)(b * 8 + h) * 65536;  // (b,h) slice, 128KB

  bf16x8 stg0, stg1, stg2, stg3;
#define SLOADH(c)                                                     \
  { const short* p_ = hG + (c) * 16384 + t * 8;                       \
    stg0 = *(const bf16x8*)(p_);        stg1 = *(const bf16x8*)(p_ + 4096); \
    stg2 = *(const bf16x8*)(p_ + 8192); stg3 = *(const bf16x8*)(p_ + 12288); }
#define SWRITEH(bufp)                                                 \
  { short* q_ = (bufp) + t * 8;                                       \
    *(bf16x8*)(q_)        = stg0;  *(bf16x8*)(q_ + 4096)  = stg1;     \
    *(bf16x8*)(q_ + 8192) = stg2;  *(bf16x8*)(q_ + 12288) = stg3; }

  bf16x8 HA[4], HB[4], cA[2], cB[2];
  f32x4 eA0, eA1, eB0, eB1;
  f32x4 accA[4] = {}, accB[4] = {};
  f32x4 accSA = {}, accSB = {};
  bf16x8 ones;
#pragma unroll
  for (int e = 0; e < 8; e++) ones[e] = (short)0x3F80;

  // prologue: chunk 0 into buf0; issue chunk-1 loads; prefetch c/er steps 0,1
  SLOADH(0);
  SWRITEH(&hbuf[0][0]);
  SLOADH(1);
  PREF_CE(0, eA0, eA1, cA);
  PREF_CE(1, eB0, eB1, cB);
  __syncthreads();

  for (int ch = 0; ch < 4; ++ch) {
    const short* hb = &hbuf[ch & 1][0];
    const int s0 = ch * 8;
    PREF_HD(hb, 0, HA);
    PREF_HD(hb, 1, HB);
#pragma unroll
    for (int sl = 0; sl < 8; sl += 2) {
      const int pa = (sl + 2 > 7) ? 7 : sl + 2;   // compile-time clamp
      const int pb = (sl + 3 > 7) ? 7 : sl + 3;
      COMP2(HA, cA, eA0, eA1);
      PREF_CE(s0 + sl + 2, eA0, eA1, cA);         // global overrun -> ws pad
      PREF_HD(hb, pa, HA);
      COMP2(HB, cB, eB0, eB1);
      PREF_CE(s0 + sl + 3, eB0, eB1, cB);
      PREF_HD(hb, pb, HB);
    }
    if (ch < 3) {
      SWRITEH(&hbuf[(ch + 1) & 1][0]);   // other buffer: its readers finished
      SLOADH(ch + 2 < 4 ? ch + 2 : 3);   // issue next-next chunk (covered by 8 steps)
      __syncthreads();                   // publish chunk ch+1
    }
  }

  const float invA = 1.0f / accSA[0];
  const float invB = 1.0f / accSB[0];
  const size_t rowA = bn + i0 + lr;
  const size_t rowB = rowA + 16;
#pragma unroll
  for (int ff = 0; ff < 4; ff++) {
    f32x4 va = accA[ff], vb = accB[ff];
    va[0]*=invA; va[1]*=invA; va[2]*=invA; va[3]*=invA;
    vb[0]*=invB; vb[1]*=invB; vb[2]*=invB; vb[3]*=invB;
    *(f32x4*)(out + rowA * HF_ + h * 64 + ff * 16 + lk * 4) = va;
    *(f32x4*)(out + rowB * HF_ + h * 64 + ff * 16 + lk * 4) = vb;
  }
}

extern "C" void kernel_launch(void* const* d_in, const int* in_sizes, int n_in,
                              void* d_out, int out_size, void* d_ws, size_t ws_size,
                              hipStream_t stream) {
  const float* x     = (const float*)d_in[0];
  const int*   adj   = (const int*)  d_in[1];
  const float* prior = (const float*)d_in[2];
  const float* W     = (const float*)d_in[3];
  const float* aL    = (const float*)d_in[4];
  const float* aR    = (const float*)d_in[5];
  const float* es    = (const float*)d_in[6];
  float* out = (float*)d_out;

  char* ws = (char*)d_ws;
  short* hAg  = (short*)ws;                                 //  0 MB,  8 MB
  short* xb   = (short*)(ws + 8u  * 1024 * 1024);           //  8 MB,  4 MB
  short* Wt   = (short*)(ws + 12u * 1024 * 1024);           // 12 MB, 256 KB
  float* el_t = (float*)(ws + 12u * 1024 * 1024 + 262144);  // 256 KB
  float* er_t = (float*)(ws + 12u * 1024 * 1024 + 524288);  // 256 KB
  short* cmat = (short*)(ws + 13u * 1024 * 1024);           // 13 MB, 16 MB (+pad)

  hipLaunchKernelGGL(k_prep, dim3(1792), dim3(256), 0, stream,
                     x, W, prior, adj, es, xb, Wt, cmat);
  hipLaunchKernelGGL(k_h,   dim3(128, 8), dim3(256), 0, stream,
                     Wt, xb, aL, aR, hAg, el_t, er_t);
  hipLaunchKernelGGL(k_attn, dim3(256), dim3(512), 0, stream,
                     hAg, el_t, er_t, cmat, out);
}